// Round 9
// baseline (766.330 us; speedup 1.0000x reference)
//
#include <hip/hip_runtime.h>
#include <hip/hip_bf16.h>
#include <stdint.h>

// ---------------- problem constants ----------------
constexpr int NN = 100000;     // nodes
constexpr int NE = 1600000;    // edges
constexpr int NG = 64;         // graphs
constexpr int S  = 192;        // row stride (elements) for node-feature buffers
constexpr int NB_SCAN = 98;    // ceil(100000/1024)
constexpr unsigned int ZOFF = (unsigned int)NN * 384u;   // byte offset of the zero row

// prep kernel grid sections (convx | indeg+slot | convw for W0..W2)
constexpr int PREP_CONVX_BLK = 12500;   // NN*32/256
constexpr int PREP_INDEG_BLK = 1563;    // ceil(NE/4/256)
constexpr int PREP_CONVW_BLK = 384;     // (24576+36864+36864)/256
constexpr int PREP_GRID = PREP_CONVX_BLK + PREP_INDEG_BLK + PREP_CONVW_BLK;

// E-GEMM geometry
constexpr int EG_BLOCKS = 391;          // ceil(NN/256), 256 src rows per block
constexpr int EG_JMAX = EG_BLOCKS * 256;  // 100096 (tail rows get E=0)

typedef __bf16 bf16x8 __attribute__((ext_vector_type(8)));
typedef float  f32x16 __attribute__((ext_vector_type(16)));
typedef float  f32x2  __attribute__((ext_vector_type(2)));

union U16x4 { uint4 u; bf16x8 b; };

// bf16(packed in uint halves) <-> f32 helpers
__device__ __forceinline__ float bl(unsigned int u) { return __uint_as_float(u << 16); }
__device__ __forceinline__ float bh(unsigned int u) { return __uint_as_float(u & 0xffff0000u); }
__device__ __forceinline__ float b16f(unsigned short u) { return __uint_as_float(((unsigned int)u) << 16); }
__device__ __forceinline__ unsigned int fb(float f) {  // f32 -> bf16 bits, RTNE
    unsigned int u = __float_as_uint(f);
    return (u + 0x7fffu + ((u >> 16) & 1u)) >> 16;
}
// packed bf16 relu: v_pk_max_f16 on raw bits decides on sign/zero only — exact for bf16.
__device__ __forceinline__ unsigned int prelu(unsigned int u) {
    unsigned int r;
    asm("v_pk_max_f16 %0, %1, %2" : "=v"(r) : "v"(u), "v"(0u));
    return r;
}

// ---------------- fused preprocessing: convx | indeg+slot | convw(W0..W2) ----------------
__global__ __launch_bounds__(256) void k_prep(const float* __restrict__ x,
                                              const int* __restrict__ ei,
                                              const float* __restrict__ W0, const float* __restrict__ W1,
                                              const float* __restrict__ W2,
                                              unsigned short* __restrict__ A_,
                                              int* __restrict__ indeg, int* __restrict__ slot,
                                              unsigned short* __restrict__ T0, unsigned short* __restrict__ T1,
                                              unsigned short* __restrict__ T2) {
    const int b = blockIdx.x;
    if (b < PREP_CONVX_BLK) {
        int id = b * 256 + threadIdx.x;
        if (id < 96) ((unsigned int*)(A_ + (size_t)NN * S))[id] = 0u;   // zero sentinel row
        int row = id >> 5, c4 = id & 31;
        float4 v = ((const float4*)x)[id];
        uint2 a;
        a.x = fb(v.x) | (fb(v.y) << 16);
        a.y = fb(v.z) | (fb(v.w) << 16);
        *(uint2*)(A_ + row * S + c4 * 4) = a;
    } else if (b < PREP_CONVX_BLK + PREP_INDEG_BLK) {
        int e4 = ((b - PREP_CONVX_BLK) * 256 + threadIdx.x) * 4;
        if (e4 < NE) {
            int4 d = *(const int4*)(ei + NE + e4);
            int4 sl;
            sl.x = atomicAdd(&indeg[d.x], 1);
            sl.y = atomicAdd(&indeg[d.y], 1);
            sl.z = atomicAdd(&indeg[d.z], 1);
            sl.w = atomicAdd(&indeg[d.w], 1);
            *(int4*)(slot + e4) = sl;
        }
    } else {
        int id = (b - PREP_CONVX_BLK - PREP_INDEG_BLK) * 256 + threadIdx.x;
        const float* W; unsigned short* T; int N, base;
        if      (id < 24576) { W = W0; T = T0; N = 192; base = 0;     }
        else if (id < 61440) { W = W1; T = T1; N = 192; base = 24576; }
        else                 { W = W2; T = T2; N = 192; base = 61440; }
        int lid = id - base;
        int ci = lid >> 3, j = lid & 7;
        int kc = ci / N, n = ci % N;
        T[lid] = (unsigned short)fb(W[(kc * 8 + j) * N + n]);
    }
}

// ---------------- scan of indeg -> offs ----------------
__global__ __launch_bounds__(1024) void k_scan1(const int* __restrict__ indeg, int* __restrict__ offs,
                                                int* __restrict__ partials) {
    __shared__ int s[1024];
    int t = threadIdx.x;
    int gid = blockIdx.x * 1024 + t;
    int v = (gid < NN) ? indeg[gid] : 0;
    s[t] = v;
    __syncthreads();
    for (int d = 1; d < 1024; d <<= 1) {
        int tv = (t >= d) ? s[t - d] : 0;
        __syncthreads();
        s[t] += tv;
        __syncthreads();
    }
    if (gid < NN) offs[gid + 1] = s[t];
    if (t == 1023) partials[blockIdx.x] = s[1023];
}

__global__ __launch_bounds__(128) void k_scan2(int* __restrict__ offs, int* __restrict__ partials) {
    __shared__ int s[128];
    int t = threadIdx.x;
    int v = (t < NB_SCAN) ? partials[t] : 0;
    s[t] = v;
    __syncthreads();
    for (int d = 1; d < 128; d <<= 1) {
        int tv = (t >= d) ? s[t - d] : 0;
        __syncthreads();
        s[t] += tv;
        __syncthreads();
    }
    if (t < NB_SCAN) partials[t] = s[t] - v;
    if (t == 0) offs[0] = 0;
}

__global__ __launch_bounds__(1024) void k_scan3(int* __restrict__ offs, const int* __restrict__ partials) {
    int gid = blockIdx.x * 1024 + threadIdx.x;
    if (gid < NN) offs[gid + 1] += partials[blockIdx.x];
}

// ---------------- atomic-free CSR fill ----------------
__global__ __launch_bounds__(256) void k_fill(const int* __restrict__ ei, const int* __restrict__ offs,
                                              const int* __restrict__ slot, int* __restrict__ csr) {
    int e4 = (blockIdx.x * 256 + threadIdx.x) * 4;
    if (e4 >= NE) return;
    int4 sv = *(const int4*)(ei + e4);
    int4 dv = *(const int4*)(ei + NE + e4);
    int4 sl = *(const int4*)(slot + e4);
    csr[offs[dv.x] + sl.x] = sv.x;
    csr[offs[dv.y] + sl.y] = sv.y;
    csr[offs[dv.z] + sl.z] = sv.z;
    csr[offs[dv.w] + sl.w] = sv.w;
}

// ---------------- aggregation (layers 0..2) ----------------
__global__ __launch_bounds__(256, 8) void k_agg192(const unsigned short* __restrict__ Ain,
                                                   unsigned short* __restrict__ Yout,
                                                   const int* __restrict__ offs,
                                                   const int* __restrict__ indeg,
                                                   const int* __restrict__ csr) {
    const int w = threadIdx.x >> 6, lane = threadIdx.x & 63;
    const int i = __builtin_amdgcn_readfirstlane(blockIdx.x * 4 + w);
    const bool act = lane < 48;
    const int deg   = __builtin_amdgcn_readfirstlane(indeg[i]);
    const int start = __builtin_amdgcn_readfirstlane(offs[i]);
    const int fo = (act ? lane : 47) * 8;
    const char* Ab = (const char*)Ain;

    f32x2 A01, A23;
    {
        uint2 p = *(const uint2*)(Ab + (size_t)i * 384 + fo);
        const float ed = 1e-7f * (float)deg;
        A01 = (f32x2){bl(p.x) + ed, bh(p.x) + ed};
        A23 = (f32x2){bl(p.y) + ed, bh(p.y) + ed};
    }

    const int* ecsr = csr + start;
    for (int e = 0; e < deg; e += 16) {
        unsigned int off[16];
#pragma unroll
        for (int k = 0; k < 16; k++) {
            int v = ecsr[e + k];
            off[k] = (e + k < deg) ? (unsigned int)v * 384u : ZOFF;
        }
        uint2 p[16];
#pragma unroll
        for (int k = 0; k < 16; k++)
            p[k] = *(const uint2*)(Ab + (size_t)off[k] + fo);
#pragma unroll
        for (int k = 0; k < 16; k++) {
            unsigned int rx = prelu(p[k].x), ry = prelu(p[k].y);
            A01 += (f32x2){bl(rx), bh(rx)};
            A23 += (f32x2){bl(ry), bh(ry)};
        }
    }
    if (act) {
        uint2 o;
        o.x = fb(A01.x) | (fb(A01.y) << 16);
        o.y = fb(A23.x) | (fb(A23.y) << 16);
        *(uint2*)(Yout + (size_t)i * S + lane * 4) = o;
    }
}

__global__ __launch_bounds__(256, 8) void k_agg128(const unsigned short* __restrict__ Ain,
                                                   unsigned short* __restrict__ Yout,
                                                   const int* __restrict__ offs,
                                                   const int* __restrict__ indeg,
                                                   const int* __restrict__ csr) {
    const int w = threadIdx.x >> 6, lane = threadIdx.x & 63;
    const int i = __builtin_amdgcn_readfirstlane(blockIdx.x * 4 + w);
    const int deg   = __builtin_amdgcn_readfirstlane(indeg[i]);
    const int start = __builtin_amdgcn_readfirstlane(offs[i]);
    const int fo = lane * 4;
    const char* Ab = (const char*)Ain;

    f32x2 A01;
    {
        unsigned int p = *(const unsigned int*)(Ab + (size_t)i * 384 + fo);
        const float ed = 1e-7f * (float)deg;
        A01 = (f32x2){bl(p) + ed, bh(p) + ed};
    }

    const int* ecsr = csr + start;
    for (int e = 0; e < deg; e += 16) {
        unsigned int off[16];
#pragma unroll
        for (int k = 0; k < 16; k++) {
            int v = ecsr[e + k];
            off[k] = (e + k < deg) ? (unsigned int)v * 384u : ZOFF;
        }
        unsigned int q[16];
#pragma unroll
        for (int k = 0; k < 16; k++)
            q[k] = *(const unsigned int*)(Ab + (size_t)off[k] + fo);
#pragma unroll
        for (int k = 0; k < 16; k++) {
            unsigned int r = prelu(q[k]);
            A01 += (f32x2){bl(r), bh(r)};
        }
    }
    *(unsigned int*)(Yout + (size_t)i * S + lane * 2) =
        fb(A01.x) | (fb(A01.y) << 16);
}

// ---------------- GEMM: h = y @ W + b (layers 0..2) ----------------
template <int K, int N>
__global__ __launch_bounds__(256) void k_gemm(const unsigned short* __restrict__ Yin,
                                              const unsigned short* __restrict__ WtC,
                                              const float* __restrict__ bias,
                                              unsigned short* __restrict__ Aout) {
    static_assert(K % 16 == 0 && N % 32 == 0, "");
    const int w = threadIdx.x >> 6, lane = threadIdx.x & 63;
    const int rt = blockIdx.x * 4 + w;
    if (rt >= (NN / 32)) return;
    const int hl = lane >> 5, lr = lane & 31;
    const int row0 = rt * 32;
    f32x16 acc[N / 32];
#pragma unroll
    for (int c = 0; c < N / 32; c++)
#pragma unroll
        for (int r = 0; r < 16; r++) acc[c][r] = 0.f;

    const unsigned short* ap = Yin + (row0 + lr) * S + hl * 8;
    const uint4* b4 = (const uint4*)WtC;
#pragma unroll
    for (int ks = 0; ks < K / 16; ks++) {
        U16x4 a;
        a.u = *(const uint4*)(ap + ks * 16);
#pragma unroll
        for (int c = 0; c < N / 32; c++) {
            U16x4 b;
            b.u = b4[(ks * 2 + hl) * N + c * 32 + lr];
            acc[c] = __builtin_amdgcn_mfma_f32_32x32x16_bf16(a.b, b.b, acc[c], 0, 0, 0);
        }
    }
#pragma unroll
    for (int c = 0; c < N / 32; c++) {
        const int col = c * 32 + lr;
        const float bc = bias[col];
#pragma unroll
        for (int r = 0; r < 16; r++) {
            const int row = row0 + (r & 3) + 8 * (r >> 2) + 4 * hl;
            Aout[row * S + col] = (unsigned short)fb(acc[c][r] + bc);
        }
    }
}

// ---------------- layer-3 replacement: E-matrix path ----------------
// hist[j][g] packed as u16 pairs in u32: count of edges j -> graph g
__global__ __launch_bounds__(256) void k_hist(const int* __restrict__ ei, const int* __restrict__ bat,
                                              unsigned int* __restrict__ hist) {
    int e2 = (blockIdx.x * 256 + threadIdx.x) * 2;
    if (e2 >= NE) return;
    int2 sv = *(const int2*)(ei + e2);
    int2 dv = *(const int2*)(ei + NE + e2);
    int g0 = bat[dv.x], g1 = bat[dv.y];
    atomicAdd(&hist[sv.x * 32 + (g0 >> 1)], 1u << (16 * (g0 & 1)));
    atomicAdd(&hist[sv.y * 32 + (g1 >> 1)], 1u << (16 * (g1 & 1)));
}

// hist -> bf16 chunk-major E: E[((j/8)*64 + g)*8 + (j%8)]; rows j>=NN get 0
__global__ __launch_bounds__(256) void k_econv(const unsigned int* __restrict__ hist,
                                               unsigned short* __restrict__ E) {
    int id = blockIdx.x * 256 + threadIdx.x;     // (j, gpair): total EG_JMAX*32
    if (id >= EG_JMAX * 32) return;
    int j = id >> 5, gp = id & 31;
    unsigned int h = (j < NN) ? hist[id] : 0u;
    unsigned short c0 = (unsigned short)fb((float)(h & 0xffffu));
    unsigned short c1 = (unsigned short)fb((float)(h >> 16));
    size_t base = ((size_t)(j >> 3) * 64 + gp * 2) * 8 + (j & 7);
    E[base] = c0;
    E[base + 8] = c1;
}

// msg-partials: P[g][f] += E[g][j] * relu(x3[j][f]) over block's 256-row K slice.
// 192 threads = 3 waves; wave w handles Nt {2w,2w+1}, both Mt. Output bf16 partials[block][64][192].
__global__ __launch_bounds__(192) void k_egemm(const unsigned short* __restrict__ A0,
                                               const unsigned short* __restrict__ E,
                                               unsigned short* __restrict__ partials) {
    const int wv = threadIdx.x >> 6, lane = threadIdx.x & 63;
    const int b = blockIdx.x;
    const int j0 = b * 256;
    const int hl = lane >> 5, lr = lane & 31;
    f32x16 acc[2][2];
#pragma unroll
    for (int m = 0; m < 2; m++)
#pragma unroll
        for (int n = 0; n < 2; n++)
#pragma unroll
            for (int r = 0; r < 16; r++) acc[m][n][r] = 0.f;

    for (int kk = 0; kk < 16; kk++) {
        const int jb8 = (j0 >> 3) + kk * 2;
        U16x4 af[2];
#pragma unroll
        for (int m = 0; m < 2; m++)
            af[m].u = *(const uint4*)(E + ((size_t)(jb8 + hl) * 64 + m * 32 + lr) * 8);
        U16x4 bf[2];
#pragma unroll
        for (int n = 0; n < 2; n++) {
            const int feat = (2 * wv + n) * 32 + lr;
#pragma unroll
            for (int tp = 0; tp < 4; tp++) {
                int je = j0 + kk * 16 + hl * 8 + tp * 2;
                int ja = min(je, NN), jb = min(je + 1, NN);
                unsigned int u0 = A0[(size_t)ja * S + feat];
                unsigned int u1 = A0[(size_t)jb * S + feat];
                ((unsigned int*)&bf[n].u)[tp] = prelu(u0 | (u1 << 16));
            }
        }
#pragma unroll
        for (int m = 0; m < 2; m++)
#pragma unroll
            for (int n = 0; n < 2; n++)
                acc[m][n] = __builtin_amdgcn_mfma_f32_32x32x16_bf16(af[m].b, bf[n].b, acc[m][n], 0, 0, 0);
    }
    unsigned short* pb = partials + (size_t)b * 12288;
#pragma unroll
    for (int m = 0; m < 2; m++)
#pragma unroll
        for (int n = 0; n < 2; n++) {
            const int f = (2 * wv + n) * 32 + lr;
#pragma unroll
            for (int r = 0; r < 16; r++) {
                const int g = m * 32 + (r & 3) + 8 * (r >> 2) + 4 * hl;
                pb[g * 192 + f] = (unsigned short)fb(acc[m][n][r]);
            }
        }
}

// reduce bf16 partials -> msg f32 [64][192]
__global__ __launch_bounds__(256) void k_reduce(const unsigned short* __restrict__ partials,
                                                float* __restrict__ msg) {
    int gf = blockIdx.x * 256 + threadIdx.x;     // 12288 total
    if (gf >= 12288) return;
    float s = 0.f;
    for (int p = 0; p < EG_BLOCKS; p++)
        s += b16f(partials[(size_t)p * 12288 + gf]);
    msg[gf] = s;
}

// ---------------- pooling (x3 sums, counts, degree sums) + head ----------------
__global__ __launch_bounds__(192) void k_pool(const unsigned short* __restrict__ A_,
                                              const int* __restrict__ batch,
                                              const int* __restrict__ indeg,
                                              float* __restrict__ sums, float* __restrict__ cnt,
                                              float* __restrict__ degsum) {
    const int b = blockIdx.x;      // 500 blocks x 200 nodes
    const int f = threadIdx.x;     // 192 features
    int n0 = b * 200;
    int n1 = min(n0 + 200, NN);
    int cur = batch[n0];
    float acc = 0.f;
    int run = 0, dacc = 0;
    for (int n = n0; n < n1; n++) {
        int g = batch[n];
        if (g != cur) {
            atomicAdd(&sums[cur * 192 + f], acc);
            if (f == 0) { atomicAdd(&cnt[cur], (float)run); atomicAdd(&degsum[cur], (float)dacc); }
            acc = 0.f; run = 0; dacc = 0; cur = g;
        }
        acc += b16f(A_[(size_t)n * S + f]);
        run++;
        if (f == 0) dacc += indeg[n];
    }
    atomicAdd(&sums[cur * 192 + f], acc);
    if (f == 0) { atomicAdd(&cnt[cur], (float)run); atomicAdd(&degsum[cur], (float)dacc); }
}

__global__ __launch_bounds__(128) void k_head(const float* __restrict__ sums, const float* __restrict__ msg,
                                              const float* __restrict__ cnt, const float* __restrict__ degsum,
                                              const float* __restrict__ W3, const float* __restrict__ b3,
                                              const float* __restrict__ Wfc, const float* __restrict__ bfc,
                                              float* __restrict__ out) {
    __shared__ float py[192];
    __shared__ float tl[128];
    __shared__ float lg[10];
    const int g = blockIdx.x, t = threadIdx.x;
    const float inv = 1.f / fmaxf(cnt[g], 1.f);
    const float ed = 1e-7f * degsum[g];
    for (int k = t; k < 192; k += 128)
        py[k] = (sums[g * 192 + k] + msg[g * 192 + k] + ed) * inv;
    __syncthreads();
    float tf = b3[t];
    for (int k = 0; k < 192; k++) tf += py[k] * W3[k * 128 + t];
    tl[t] = tf;
    __syncthreads();
    if (t < 10) {
        float s = bfc[t];
        for (int f = 0; f < 128; f++) s += tl[f] * Wfc[f * 10 + t];
        lg[t] = s;
    }
    __syncthreads();
    if (t < 10) {
        float m = lg[0];
        for (int k = 1; k < 10; k++) m = fmaxf(m, lg[k]);
        float se = 0.f;
        for (int k = 0; k < 10; k++) se += expf(lg[k] - m);
        out[g * 10 + t] = lg[t] - m - logf(se);
    }
}

// ---------------- workspace layout (bytes) ----------------
constexpr size_t A0_OFF     = 0;                    // 38,400,384 (incl zero row NN)
constexpr size_t A1_OFF     = 38400384;             // 38,400,000: slot -> y -> hist/E/partials
constexpr size_t HIST_REL   = 0;                    // 12,800,000 (NN*32*4)
constexpr size_t E_REL      = 12800000;             // 12,812,288 (12512*64*8*2)
constexpr size_t PARTS_REL  = 25612288;             // 9,609,216 (391*12288*2) -> ends 35,221,504
constexpr size_t CSR_OFF    = 76800384;             // 6,400,000
constexpr size_t OFFS_OFF   = 83200384;             // 400,128
constexpr size_t INDEG_OFF  = 83600512;             // 400,000
constexpr size_t PART_OFF   = 84000512;             // 512
constexpr size_t WT0_OFF    = 84001024;             // 49,152
constexpr size_t WT1_OFF    = 84050176;             // 73,728
constexpr size_t WT2_OFF    = 84123904;             // 73,728
constexpr size_t SUMS_OFF   = 84197632;             // 49,152
constexpr size_t CNT_OFF    = 84246784;             // 256
constexpr size_t DEGS_OFF   = 84247040;             // 256
constexpr size_t MSG_OFF    = 84247296;             // 49,152 -> ends 84,296,448 (< R8's 84.68M)

extern "C" void kernel_launch(void* const* d_in, const int* in_sizes, int n_in,
                              void* d_out, int out_size, void* d_ws, size_t ws_size,
                              hipStream_t stream) {
    const float* x   = (const float*)d_in[0];
    const float* W0  = (const float*)d_in[1];
    const float* b0  = (const float*)d_in[2];
    const float* W1  = (const float*)d_in[3];
    const float* b1  = (const float*)d_in[4];
    const float* W2  = (const float*)d_in[5];
    const float* b2  = (const float*)d_in[6];
    const float* W3  = (const float*)d_in[7];
    const float* b3  = (const float*)d_in[8];
    const float* Wfc = (const float*)d_in[9];
    const float* bfc = (const float*)d_in[10];
    const int*   ei  = (const int*)d_in[11];
    const int*   bat = (const int*)d_in[12];
    float* out = (float*)d_out;

    char* ws = (char*)d_ws;
    unsigned short* A0  = (unsigned short*)(ws + A0_OFF);
    unsigned short* A1  = (unsigned short*)(ws + A1_OFF);
    int* slot   = (int*)(ws + A1_OFF);
    unsigned int*   hist  = (unsigned int*)(ws + A1_OFF + HIST_REL);
    unsigned short* Ebf   = (unsigned short*)(ws + A1_OFF + E_REL);
    unsigned short* parts = (unsigned short*)(ws + A1_OFF + PARTS_REL);
    int* csr    = (int*)(ws + CSR_OFF);
    int* offs   = (int*)(ws + OFFS_OFF);
    int* indeg  = (int*)(ws + INDEG_OFF);
    int* part   = (int*)(ws + PART_OFF);
    unsigned short* Wt0 = (unsigned short*)(ws + WT0_OFF);
    unsigned short* Wt1 = (unsigned short*)(ws + WT1_OFF);
    unsigned short* Wt2 = (unsigned short*)(ws + WT2_OFF);
    float* sums   = (float*)(ws + SUMS_OFF);
    float* cnt    = (float*)(ws + CNT_OFF);
    float* degsum = (float*)(ws + DEGS_OFF);
    float* msg    = (float*)(ws + MSG_OFF);

    // zero indeg; zero sums+cnt+degsum (contiguous 49,664B)
    hipMemsetAsync(ws + INDEG_OFF, 0, 400000, stream);
    hipMemsetAsync(ws + SUMS_OFF, 0, 49664, stream);

    // fused preprocessing
    k_prep<<<PREP_GRID, 256, 0, stream>>>(x, ei, W0, W1, W2, A0, indeg, slot, Wt0, Wt1, Wt2);

    // offs = exclusive scan(indeg); atomic-free CSR fill
    k_scan1<<<NB_SCAN, 1024, 0, stream>>>(indeg, offs, part);
    k_scan2<<<1, 128, 0, stream>>>(offs, part);
    k_scan3<<<NB_SCAN, 1024, 0, stream>>>(offs, part);
    k_fill<<<(NE / 4 + 255) / 256, 256, 0, stream>>>(ei, offs, slot, csr);

    const int AGG_GRID  = NN / 4;                   // 25000 blocks
    const int GEMM_GRID = (NN / 32 + 3) / 4;        // 782 blocks

    // layers 0..2 (ping-pong A0 <-> A1)
    k_agg128<<<AGG_GRID, 256, 0, stream>>>(A0, A1, offs, indeg, csr);
    k_gemm<128, 192><<<GEMM_GRID, 256, 0, stream>>>(A1, Wt0, b0, A0);
    k_agg192<<<AGG_GRID, 256, 0, stream>>>(A0, A1, offs, indeg, csr);
    k_gemm<192, 192><<<GEMM_GRID, 256, 0, stream>>>(A1, Wt1, b1, A0);
    k_agg192<<<AGG_GRID, 256, 0, stream>>>(A0, A1, offs, indeg, csr);
    k_gemm<192, 192><<<GEMM_GRID, 256, 0, stream>>>(A1, Wt2, b2, A0);   // A0 = x3

    // layer 3 via linearity: pooled(y3) = pooled(x3) + eps*degsum + E @ relu(x3)
    hipMemsetAsync(ws + A1_OFF + HIST_REL, 0, 12800000, stream);        // y2 dead; reuse A1
    k_hist<<<NE / 512, 256, 0, stream>>>(ei, bat, hist);
    k_econv<<<(EG_JMAX * 32) / 256, 256, 0, stream>>>(hist, Ebf);
    k_egemm<<<EG_BLOCKS, 192, 0, stream>>>(A0, Ebf, parts);
    k_reduce<<<48, 256, 0, stream>>>(parts, msg);
    k_pool<<<500, 192, 0, stream>>>(A0, bat, indeg, sums, cnt, degsum);
    k_head<<<NG, 128, 0, stream>>>(sums, msg, cnt, degsum, W3, b3, Wfc, bfc, out);
}

// Round 10
// 713.924 us; speedup vs baseline: 1.0734x; 1.0734x over previous
//
#include <hip/hip_runtime.h>
#include <hip/hip_bf16.h>
#include <stdint.h>

// ---------------- problem constants ----------------
constexpr int NN = 100000;     // nodes
constexpr int NE = 1600000;    // edges
constexpr int NG = 64;         // graphs
constexpr int S  = 192;        // row stride (elements) for node-feature buffers
constexpr int NB_SCAN = 98;    // ceil(100000/1024)
constexpr unsigned int ZOFF = (unsigned int)NN * 384u;   // byte offset of the zero row

// prep kernel grid sections (convx | indeg+slot | convw(W0..W2) | nstart)
constexpr int PREP_CONVX_BLK = 12500;   // NN*32/256
constexpr int PREP_INDEG_BLK = 1563;    // ceil(NE/4/256)
constexpr int PREP_CONVW_BLK = 384;     // (24576+36864+36864)/256
constexpr int PREP_GB_BLK    = 391;     // ceil(NN/256)
constexpr int PREP_GRID = PREP_CONVX_BLK + PREP_INDEG_BLK + PREP_CONVW_BLK + PREP_GB_BLK;

// E-GEMM geometry
constexpr int EG_BLOCKS = 391;            // ceil(NN/256), 256 src rows per block
constexpr int HROW = 50048;               // hist row length in u32 (EG_BLOCKS*256/2)

typedef __bf16 bf16x8 __attribute__((ext_vector_type(8)));
typedef float  f32x16 __attribute__((ext_vector_type(16)));
typedef float  f32x2  __attribute__((ext_vector_type(2)));

union U16x4 { uint4 u; bf16x8 b; };

// bf16(packed in uint halves) <-> f32 helpers
__device__ __forceinline__ float bl(unsigned int u) { return __uint_as_float(u << 16); }
__device__ __forceinline__ float bh(unsigned int u) { return __uint_as_float(u & 0xffff0000u); }
__device__ __forceinline__ float b16f(unsigned short u) { return __uint_as_float(((unsigned int)u) << 16); }
__device__ __forceinline__ unsigned int fb(float f) {  // f32 -> bf16 bits, RTNE
    unsigned int u = __float_as_uint(f);
    return (u + 0x7fffu + ((u >> 16) & 1u)) >> 16;
}
// packed bf16 relu: v_pk_max_f16 on raw bits decides on sign/zero only — exact for bf16.
__device__ __forceinline__ unsigned int prelu(unsigned int u) {
    unsigned int r;
    asm("v_pk_max_f16 %0, %1, %2" : "=v"(r) : "v"(u), "v"(0u));
    return r;
}
// two u16 counts -> packed bf16 pair (exact for counts <= 256)
__device__ __forceinline__ unsigned int cnt2bf(unsigned int h) {
    float f0 = (float)(h & 0xffffu);
    float f1 = (float)(h >> 16);
    return (__float_as_uint(f0) >> 16) | (__float_as_uint(f1) & 0xffff0000u);
}

// ---------------- fused preprocessing: convx | indeg+slot | convw | nstart ----------------
__global__ __launch_bounds__(256) void k_prep(const float* __restrict__ x,
                                              const int* __restrict__ ei,
                                              const int* __restrict__ bat,
                                              const float* __restrict__ W0, const float* __restrict__ W1,
                                              const float* __restrict__ W2,
                                              unsigned short* __restrict__ A_,
                                              int* __restrict__ indeg, int* __restrict__ slot,
                                              unsigned short* __restrict__ T0, unsigned short* __restrict__ T1,
                                              unsigned short* __restrict__ T2,
                                              int* __restrict__ nstart) {
    const int b = blockIdx.x;
    if (b < PREP_CONVX_BLK) {
        int id = b * 256 + threadIdx.x;
        if (id < 96) ((unsigned int*)(A_ + (size_t)NN * S))[id] = 0u;   // zero sentinel row
        int row = id >> 5, c4 = id & 31;
        float4 v = ((const float4*)x)[id];
        uint2 a;
        a.x = fb(v.x) | (fb(v.y) << 16);
        a.y = fb(v.z) | (fb(v.w) << 16);
        *(uint2*)(A_ + row * S + c4 * 4) = a;
    } else if (b < PREP_CONVX_BLK + PREP_INDEG_BLK) {
        int e4 = ((b - PREP_CONVX_BLK) * 256 + threadIdx.x) * 4;
        if (e4 < NE) {
            int4 d = *(const int4*)(ei + NE + e4);
            int4 sl;
            sl.x = atomicAdd(&indeg[d.x], 1);
            sl.y = atomicAdd(&indeg[d.y], 1);
            sl.z = atomicAdd(&indeg[d.z], 1);
            sl.w = atomicAdd(&indeg[d.w], 1);
            *(int4*)(slot + e4) = sl;
        }
    } else if (b < PREP_CONVX_BLK + PREP_INDEG_BLK + PREP_CONVW_BLK) {
        int id = (b - PREP_CONVX_BLK - PREP_INDEG_BLK) * 256 + threadIdx.x;
        const float* W; unsigned short* T; int N, base;
        if      (id < 24576) { W = W0; T = T0; N = 192; base = 0;     }
        else if (id < 61440) { W = W1; T = T1; N = 192; base = 24576; }
        else                 { W = W2; T = T2; N = 192; base = 61440; }
        int lid = id - base;
        int ci = lid >> 3, j = lid & 7;
        int kc = ci / N, n = ci % N;
        T[lid] = (unsigned short)fb(W[(kc * 8 + j) * N + n]);
    } else {
        // nstart[g] = first node n with bat[n] >= g (batch sorted); empty graphs ok
        int n = (b - PREP_CONVX_BLK - PREP_INDEG_BLK - PREP_CONVW_BLK) * 256 + threadIdx.x;
        if (n < NN) {
            int b0 = bat[n];
            int bprev = (n == 0) ? -1 : bat[n - 1];
            for (int g = bprev + 1; g <= b0; g++) nstart[g] = n;
            if (n == NN - 1)
                for (int g = b0 + 1; g < NG; g++) nstart[g] = NN;
        }
    }
}

// ---------------- scan of indeg -> offs ----------------
__global__ __launch_bounds__(1024) void k_scan1(const int* __restrict__ indeg, int* __restrict__ offs,
                                                int* __restrict__ partials) {
    __shared__ int s[1024];
    int t = threadIdx.x;
    int gid = blockIdx.x * 1024 + t;
    int v = (gid < NN) ? indeg[gid] : 0;
    s[t] = v;
    __syncthreads();
    for (int d = 1; d < 1024; d <<= 1) {
        int tv = (t >= d) ? s[t - d] : 0;
        __syncthreads();
        s[t] += tv;
        __syncthreads();
    }
    if (gid < NN) offs[gid + 1] = s[t];
    if (t == 1023) partials[blockIdx.x] = s[1023];
}

__global__ __launch_bounds__(128) void k_scan2(int* __restrict__ offs, int* __restrict__ partials) {
    __shared__ int s[128];
    int t = threadIdx.x;
    int v = (t < NB_SCAN) ? partials[t] : 0;
    s[t] = v;
    __syncthreads();
    for (int d = 1; d < 128; d <<= 1) {
        int tv = (t >= d) ? s[t - d] : 0;
        __syncthreads();
        s[t] += tv;
        __syncthreads();
    }
    if (t < NB_SCAN) partials[t] = s[t] - v;
    if (t == 0) offs[0] = 0;
}

__global__ __launch_bounds__(1024) void k_scan3(int* __restrict__ offs, const int* __restrict__ partials) {
    int gid = blockIdx.x * 1024 + threadIdx.x;
    if (gid < NN) offs[gid + 1] += partials[blockIdx.x];
}

// ---------------- atomic-free CSR fill ----------------
__global__ __launch_bounds__(256) void k_fill(const int* __restrict__ ei, const int* __restrict__ offs,
                                              const int* __restrict__ slot, int* __restrict__ csr) {
    int e4 = (blockIdx.x * 256 + threadIdx.x) * 4;
    if (e4 >= NE) return;
    int4 sv = *(const int4*)(ei + e4);
    int4 dv = *(const int4*)(ei + NE + e4);
    int4 sl = *(const int4*)(slot + e4);
    csr[offs[dv.x] + sl.x] = sv.x;
    csr[offs[dv.y] + sl.y] = sv.y;
    csr[offs[dv.z] + sl.z] = sv.z;
    csr[offs[dv.w] + sl.w] = sv.w;
}

// ---------------- aggregation (layers 0..2) ----------------
__global__ __launch_bounds__(256, 8) void k_agg192(const unsigned short* __restrict__ Ain,
                                                   unsigned short* __restrict__ Yout,
                                                   const int* __restrict__ offs,
                                                   const int* __restrict__ indeg,
                                                   const int* __restrict__ csr) {
    const int w = threadIdx.x >> 6, lane = threadIdx.x & 63;
    const int i = __builtin_amdgcn_readfirstlane(blockIdx.x * 4 + w);
    const bool act = lane < 48;
    const int deg   = __builtin_amdgcn_readfirstlane(indeg[i]);
    const int start = __builtin_amdgcn_readfirstlane(offs[i]);
    const int fo = (act ? lane : 47) * 8;
    const char* Ab = (const char*)Ain;

    f32x2 A01, A23;
    {
        uint2 p = *(const uint2*)(Ab + (size_t)i * 384 + fo);
        const float ed = 1e-7f * (float)deg;
        A01 = (f32x2){bl(p.x) + ed, bh(p.x) + ed};
        A23 = (f32x2){bl(p.y) + ed, bh(p.y) + ed};
    }

    const int* ecsr = csr + start;
    for (int e = 0; e < deg; e += 16) {
        unsigned int off[16];
#pragma unroll
        for (int k = 0; k < 16; k++) {
            int v = ecsr[e + k];
            off[k] = (e + k < deg) ? (unsigned int)v * 384u : ZOFF;
        }
        uint2 p[16];
#pragma unroll
        for (int k = 0; k < 16; k++)
            p[k] = *(const uint2*)(Ab + (size_t)off[k] + fo);
#pragma unroll
        for (int k = 0; k < 16; k++) {
            unsigned int rx = prelu(p[k].x), ry = prelu(p[k].y);
            A01 += (f32x2){bl(rx), bh(rx)};
            A23 += (f32x2){bl(ry), bh(ry)};
        }
    }
    if (act) {
        uint2 o;
        o.x = fb(A01.x) | (fb(A01.y) << 16);
        o.y = fb(A23.x) | (fb(A23.y) << 16);
        *(uint2*)(Yout + (size_t)i * S + lane * 4) = o;
    }
}

__global__ __launch_bounds__(256, 8) void k_agg128(const unsigned short* __restrict__ Ain,
                                                   unsigned short* __restrict__ Yout,
                                                   const int* __restrict__ offs,
                                                   const int* __restrict__ indeg,
                                                   const int* __restrict__ csr) {
    const int w = threadIdx.x >> 6, lane = threadIdx.x & 63;
    const int i = __builtin_amdgcn_readfirstlane(blockIdx.x * 4 + w);
    const int deg   = __builtin_amdgcn_readfirstlane(indeg[i]);
    const int start = __builtin_amdgcn_readfirstlane(offs[i]);
    const int fo = lane * 4;
    const char* Ab = (const char*)Ain;

    f32x2 A01;
    {
        unsigned int p = *(const unsigned int*)(Ab + (size_t)i * 384 + fo);
        const float ed = 1e-7f * (float)deg;
        A01 = (f32x2){bl(p) + ed, bh(p) + ed};
    }

    const int* ecsr = csr + start;
    for (int e = 0; e < deg; e += 16) {
        unsigned int off[16];
#pragma unroll
        for (int k = 0; k < 16; k++) {
            int v = ecsr[e + k];
            off[k] = (e + k < deg) ? (unsigned int)v * 384u : ZOFF;
        }
        unsigned int q[16];
#pragma unroll
        for (int k = 0; k < 16; k++)
            q[k] = *(const unsigned int*)(Ab + (size_t)off[k] + fo);
#pragma unroll
        for (int k = 0; k < 16; k++) {
            unsigned int r = prelu(q[k]);
            A01 += (f32x2){bl(r), bh(r)};
        }
    }
    *(unsigned int*)(Yout + (size_t)i * S + lane * 2) =
        fb(A01.x) | (fb(A01.y) << 16);
}

// ---------------- GEMM: h = y @ W + b (layers 0..2) ----------------
template <int K, int N>
__global__ __launch_bounds__(256) void k_gemm(const unsigned short* __restrict__ Yin,
                                              const unsigned short* __restrict__ WtC,
                                              const float* __restrict__ bias,
                                              unsigned short* __restrict__ Aout) {
    static_assert(K % 16 == 0 && N % 32 == 0, "");
    const int w = threadIdx.x >> 6, lane = threadIdx.x & 63;
    const int rt = blockIdx.x * 4 + w;
    if (rt >= (NN / 32)) return;
    const int hl = lane >> 5, lr = lane & 31;
    const int row0 = rt * 32;
    f32x16 acc[N / 32];
#pragma unroll
    for (int c = 0; c < N / 32; c++)
#pragma unroll
        for (int r = 0; r < 16; r++) acc[c][r] = 0.f;

    const unsigned short* ap = Yin + (row0 + lr) * S + hl * 8;
    const uint4* b4 = (const uint4*)WtC;
#pragma unroll
    for (int ks = 0; ks < K / 16; ks++) {
        U16x4 a;
        a.u = *(const uint4*)(ap + ks * 16);
#pragma unroll
        for (int c = 0; c < N / 32; c++) {
            U16x4 b;
            b.u = b4[(ks * 2 + hl) * N + c * 32 + lr];
            acc[c] = __builtin_amdgcn_mfma_f32_32x32x16_bf16(a.b, b.b, acc[c], 0, 0, 0);
        }
    }
#pragma unroll
    for (int c = 0; c < N / 32; c++) {
        const int col = c * 32 + lr;
        const float bc = bias[col];
#pragma unroll
        for (int r = 0; r < 16; r++) {
            const int row = row0 + (r & 3) + 8 * (r >> 2) + 4 * hl;
            Aout[row * S + col] = (unsigned short)fb(acc[c][r] + bc);
        }
    }
}

// ---------------- layer-3 replacement: E-matrix path ----------------
// hist[g][j] u16-pair packed: count of edges j -> graph g. Built graph-major via the
// graph-contiguous CSR: block (g,q) walks a quarter of graph g's csr range — coalesced
// reads, atomics confined to one 200KB hist row.
__global__ __launch_bounds__(256) void k_hist(const int* __restrict__ csr, const int* __restrict__ offs,
                                              const int* __restrict__ nstart,
                                              unsigned int* __restrict__ hist) {
    const int g = blockIdx.x >> 2, q = blockIdx.x & 3;
    const int s0 = offs[nstart[g]];
    const int s1 = (g == NG - 1) ? NE : offs[nstart[g + 1]];
    const int len = s1 - s0;
    const int qs = s0 + (int)(((long long)len * q) >> 2);
    const int qe = s0 + (int)(((long long)len * (q + 1)) >> 2);
    unsigned int* hrow = hist + (size_t)g * HROW;
    for (int p = qs + threadIdx.x; p < qe; p += 256) {
        int src = csr[p];
        atomicAdd(&hrow[src >> 1], 1u << (16 * (src & 1)));
    }
}

// msg-partials: P[g][f] += count(j->g) * relu(x3[j][f]) over block's 256-row K slice.
// 384 threads = 6 waves; wave wv owns feat tile wv (32 feats), both 32-g tiles.
// E A-fragment built on the fly from hist (u16 counts -> bf16, exact).
__global__ __launch_bounds__(384) void k_egemm(const unsigned short* __restrict__ A0,
                                               const unsigned int* __restrict__ hist,
                                               float* __restrict__ partials) {
    const int wv = threadIdx.x >> 6, lane = threadIdx.x & 63;
    const int b = blockIdx.x;
    const int j0 = b * 256;
    const int hl = lane >> 5, lr = lane & 31;
    const int feat = wv * 32 + lr;
    f32x16 acc[2];
#pragma unroll
    for (int m = 0; m < 2; m++)
#pragma unroll
        for (int r = 0; r < 16; r++) acc[m][r] = 0.f;

    for (int kk = 0; kk < 16; kk++) {
        // A-operand: counts for g = m*32+lr, j = j0+kk*16+hl*8 .. +8
        const int jh = (j0 >> 1) + kk * 8 + hl * 4;
        U16x4 af[2];
#pragma unroll
        for (int m = 0; m < 2; m++) {
            uint4 h = *(const uint4*)(hist + (size_t)(m * 32 + lr) * HROW + jh);
            af[m].u = (uint4){cnt2bf(h.x), cnt2bf(h.y), cnt2bf(h.z), cnt2bf(h.w)};
        }
        // B-operand: relu(x3[j][feat]) for the same 8 j
        U16x4 bf;
#pragma unroll
        for (int tp = 0; tp < 4; tp++) {
            int je = j0 + kk * 16 + hl * 8 + tp * 2;
            int ja = min(je, NN), jb = min(je + 1, NN);   // sentinel zero row
            unsigned int u0 = A0[(size_t)ja * S + feat];
            unsigned int u1 = A0[(size_t)jb * S + feat];
            ((unsigned int*)&bf.u)[tp] = prelu(u0 | (u1 << 16));
        }
#pragma unroll
        for (int m = 0; m < 2; m++)
            acc[m] = __builtin_amdgcn_mfma_f32_32x32x16_bf16(af[m].b, bf.b, acc[m], 0, 0, 0);
    }
    float* pb = partials + (size_t)b * 12288;
#pragma unroll
    for (int m = 0; m < 2; m++)
#pragma unroll
        for (int r = 0; r < 16; r++) {
            const int g = m * 32 + (r & 3) + 8 * (r >> 2) + 4 * hl;
            pb[g * 192 + feat] = acc[m][r];
        }
}

// reduce f32 partials -> msg f32 [64][192]
__global__ __launch_bounds__(256) void k_reduce(const float* __restrict__ partials,
                                                float* __restrict__ msg) {
    int gf = blockIdx.x * 256 + threadIdx.x;     // 12288 total
    if (gf >= 12288) return;
    float s = 0.f;
    for (int p = 0; p < EG_BLOCKS; p++)
        s += partials[(size_t)p * 12288 + gf];
    msg[gf] = s;
}

// ---------------- pooling (x3 sums, counts, degree sums) + head ----------------
__global__ __launch_bounds__(192) void k_pool(const unsigned short* __restrict__ A_,
                                              const int* __restrict__ batch,
                                              const int* __restrict__ indeg,
                                              float* __restrict__ sums, float* __restrict__ cnt,
                                              float* __restrict__ degsum) {
    const int b = blockIdx.x;      // 500 blocks x 200 nodes
    const int f = threadIdx.x;     // 192 features
    int n0 = b * 200;
    int n1 = min(n0 + 200, NN);
    int cur = batch[n0];
    float acc = 0.f;
    int run = 0, dacc = 0;
    for (int n = n0; n < n1; n++) {
        int g = batch[n];
        if (g != cur) {
            atomicAdd(&sums[cur * 192 + f], acc);
            if (f == 0) { atomicAdd(&cnt[cur], (float)run); atomicAdd(&degsum[cur], (float)dacc); }
            acc = 0.f; run = 0; dacc = 0; cur = g;
        }
        acc += b16f(A_[(size_t)n * S + f]);
        run++;
        if (f == 0) dacc += indeg[n];
    }
    atomicAdd(&sums[cur * 192 + f], acc);
    if (f == 0) { atomicAdd(&cnt[cur], (float)run); atomicAdd(&degsum[cur], (float)dacc); }
}

__global__ __launch_bounds__(128) void k_head(const float* __restrict__ sums, const float* __restrict__ msg,
                                              const float* __restrict__ cnt, const float* __restrict__ degsum,
                                              const float* __restrict__ W3, const float* __restrict__ b3,
                                              const float* __restrict__ Wfc, const float* __restrict__ bfc,
                                              float* __restrict__ out) {
    __shared__ float py[192];
    __shared__ float tl[128];
    __shared__ float lg[10];
    const int g = blockIdx.x, t = threadIdx.x;
    const float inv = 1.f / fmaxf(cnt[g], 1.f);
    const float ed = 1e-7f * degsum[g];
    for (int k = t; k < 192; k += 128)
        py[k] = (sums[g * 192 + k] + msg[g * 192 + k] + ed) * inv;
    __syncthreads();
    float tf = b3[t];
    for (int k = 0; k < 192; k++) tf += py[k] * W3[k * 128 + t];
    tl[t] = tf;
    __syncthreads();
    if (t < 10) {
        float s = bfc[t];
        for (int f = 0; f < 128; f++) s += tl[f] * Wfc[f * 10 + t];
        lg[t] = s;
    }
    __syncthreads();
    if (t < 10) {
        float m = lg[0];
        for (int k = 1; k < 10; k++) m = fmaxf(m, lg[k]);
        float se = 0.f;
        for (int k = 0; k < 10; k++) se += expf(lg[k] - m);
        out[g * 10 + t] = lg[t] - m - logf(se);
    }
}

// ---------------- workspace layout (bytes) ----------------
constexpr size_t A0_OFF     = 0;                    // 38,400,384 (incl zero row NN)
constexpr size_t A1_OFF     = 38400384;             // 38,400,000: slot -> y -> hist/partials
constexpr size_t HIST_REL   = 0;                    // 12,812,288 (64*50048*4)
constexpr size_t PARTS_REL  = 12812288;             // 19,218,432 (391*12288*4) -> ends 32,030,720
constexpr size_t CSR_OFF    = 76800384;             // 6,400,000
constexpr size_t OFFS_OFF   = 83200384;             // 400,128
constexpr size_t INDEG_OFF  = 83600512;             // 400,000
constexpr size_t PART_OFF   = 84000512;             // 512
constexpr size_t NSTART_OFF = 84001024;             // 256
constexpr size_t WT0_OFF    = 84001280;             // 49,152
constexpr size_t WT1_OFF    = 84050432;             // 73,728
constexpr size_t WT2_OFF    = 84124160;             // 73,728
constexpr size_t SUMS_OFF   = 84197888;             // 49,152
constexpr size_t CNT_OFF    = 84247040;             // 256
constexpr size_t DEGS_OFF   = 84247296;             // 256
constexpr size_t MSG_OFF    = 84247552;             // 49,152 -> ends 84,296,704

extern "C" void kernel_launch(void* const* d_in, const int* in_sizes, int n_in,
                              void* d_out, int out_size, void* d_ws, size_t ws_size,
                              hipStream_t stream) {
    const float* x   = (const float*)d_in[0];
    const float* W0  = (const float*)d_in[1];
    const float* b0  = (const float*)d_in[2];
    const float* W1  = (const float*)d_in[3];
    const float* b1  = (const float*)d_in[4];
    const float* W2  = (const float*)d_in[5];
    const float* b2  = (const float*)d_in[6];
    const float* W3  = (const float*)d_in[7];
    const float* b3  = (const float*)d_in[8];
    const float* Wfc = (const float*)d_in[9];
    const float* bfc = (const float*)d_in[10];
    const int*   ei  = (const int*)d_in[11];
    const int*   bat = (const int*)d_in[12];
    float* out = (float*)d_out;

    char* ws = (char*)d_ws;
    unsigned short* A0  = (unsigned short*)(ws + A0_OFF);
    unsigned short* A1  = (unsigned short*)(ws + A1_OFF);
    int* slot   = (int*)(ws + A1_OFF);
    unsigned int* hist  = (unsigned int*)(ws + A1_OFF + HIST_REL);
    float* parts        = (float*)(ws + A1_OFF + PARTS_REL);
    int* csr    = (int*)(ws + CSR_OFF);
    int* offs   = (int*)(ws + OFFS_OFF);
    int* indeg  = (int*)(ws + INDEG_OFF);
    int* part   = (int*)(ws + PART_OFF);
    int* nstart = (int*)(ws + NSTART_OFF);
    unsigned short* Wt0 = (unsigned short*)(ws + WT0_OFF);
    unsigned short* Wt1 = (unsigned short*)(ws + WT1_OFF);
    unsigned short* Wt2 = (unsigned short*)(ws + WT2_OFF);
    float* sums   = (float*)(ws + SUMS_OFF);
    float* cnt    = (float*)(ws + CNT_OFF);
    float* degsum = (float*)(ws + DEGS_OFF);
    float* msg    = (float*)(ws + MSG_OFF);

    // zero indeg; zero sums+cnt+degsum (contiguous 49,664B)
    hipMemsetAsync(ws + INDEG_OFF, 0, 400000, stream);
    hipMemsetAsync(ws + SUMS_OFF, 0, 49664, stream);

    // fused preprocessing
    k_prep<<<PREP_GRID, 256, 0, stream>>>(x, ei, bat, W0, W1, W2, A0, indeg, slot,
                                          Wt0, Wt1, Wt2, nstart);

    // offs = exclusive scan(indeg); atomic-free CSR fill
    k_scan1<<<NB_SCAN, 1024, 0, stream>>>(indeg, offs, part);
    k_scan2<<<1, 128, 0, stream>>>(offs, part);
    k_scan3<<<NB_SCAN, 1024, 0, stream>>>(offs, part);
    k_fill<<<(NE / 4 + 255) / 256, 256, 0, stream>>>(ei, offs, slot, csr);

    const int AGG_GRID  = NN / 4;                   // 25000 blocks
    const int GEMM_GRID = (NN / 32 + 3) / 4;        // 782 blocks

    // layers 0..2 (ping-pong A0 <-> A1)
    k_agg128<<<AGG_GRID, 256, 0, stream>>>(A0, A1, offs, indeg, csr);
    k_gemm<128, 192><<<GEMM_GRID, 256, 0, stream>>>(A1, Wt0, b0, A0);
    k_agg192<<<AGG_GRID, 256, 0, stream>>>(A0, A1, offs, indeg, csr);
    k_gemm<192, 192><<<GEMM_GRID, 256, 0, stream>>>(A1, Wt1, b1, A0);
    k_agg192<<<AGG_GRID, 256, 0, stream>>>(A0, A1, offs, indeg, csr);
    k_gemm<192, 192><<<GEMM_GRID, 256, 0, stream>>>(A1, Wt2, b2, A0);   // A0 = x3

    // layer 3 via linearity: pooled(y3) = pooled(x3) + eps*degsum + E @ relu(x3)
    hipMemsetAsync(ws + A1_OFF + HIST_REL, 0, 12812288, stream);        // y2 dead; reuse A1
    k_hist<<<NG * 4, 256, 0, stream>>>(csr, offs, nstart, hist);
    k_egemm<<<EG_BLOCKS, 384, 0, stream>>>(A0, hist, parts);
    k_reduce<<<48, 256, 0, stream>>>(parts, msg);
    k_pool<<<500, 192, 0, stream>>>(A0, bat, indeg, sums, cnt, degsum);
    k_head<<<NG, 128, 0, stream>>>(sums, msg, cnt, degsum, W3, b3, Wfc, bfc, out);
}